// Round 1
// 253.452 us; speedup vs baseline: 1.0139x; 1.0139x over previous
//
#include <hip/hip_runtime.h>

// Antecedents: out[n, r] = prod_v memberships[v, n, s_v(r)]
// r = s0*4^5 + s1*4^4 + s2*4^3 + s3*4^2 + s4*4 + s5  (s5 fastest)
//
// memberships layout: [N_VARS=6, N_SAMPLES=16384, N_SETS=4] fp32
// output: [16384, 4096] fp32 = 268 MB -> write-BW bound (~43 us roofline)
//
// R2 post-mortem: `nt` stores bypass L2 write combining -> capped ~1 TB/s.
// R3 theory: rocprof shows the kernel dispatch itself < 166 us (absent from
// top-5; the 167 us rows are the harness's 1 GiB output poison fill). The
// kernel-side limiter is per-block overhead: 16384 blocks x 4 stores/thread.
// This version: 2048 blocks x 8 samples each -> 128 KB contiguous output per
// block, 32 independent store instrs/thread, single vectorized LDS stage.

constexpr int N_VARS    = 6;
constexpr int N_SAMPLES = 16384;
constexpr int N_SETS    = 4;
constexpr int N_COMBOS  = 1024;  // float4s per sample row (s0..s4); s5 in lanes
constexpr int SPB       = 8;     // samples per block
constexpr int N_BLOCKS  = N_SAMPLES / SPB;  // 2048 = 8 blocks/CU on 256 CUs

typedef float v4f __attribute__((ext_vector_type(4)));

__global__ __launch_bounds__(256, 8) void antecedents_kernel(
    const float* __restrict__ m, v4f* __restrict__ out4) {
  const int t  = threadIdx.x;            // 0..255
  const int n0 = blockIdx.x * SPB;       // first sample of this block

  // Stage memberships for 8 samples. m[v] is [N_SAMPLES][N_SETS], so the
  // 8 samples' values are 32 contiguous floats per variable: 6 x 8 = 48
  // float4 loads, one per thread t<48. Input is 1.5 MB total -> L2-resident.
  __shared__ __align__(16) float sm[N_VARS][SPB][N_SETS];
  if (t < N_VARS * SPB) {  // 48 threads
    const int v = t >> 3, i = t & 7;
    reinterpret_cast<v4f&>(sm[v][i][0]) =
        *reinterpret_cast<const v4f*>(m + (size_t)v * (N_SAMPLES * N_SETS) +
                                      (size_t)(n0 + i) * N_SETS);
  }
  __syncthreads();

  // Per-thread fixed set indices for vars 1..4 (combo c = s0*256 + t).
  const int s1 = (t >> 6) & 3;   // constant per wave -> LDS broadcast
  const int s2 = (t >> 4) & 3;
  const int s3 = (t >> 2) & 3;
  const int s4 = t & 3;

#pragma unroll
  for (int i = 0; i < SPB; ++i) {
    const float q = sm[1][i][s1] * sm[2][i][s2] * sm[3][i][s3] * sm[4][i][s4];
    const v4f m5  = reinterpret_cast<const v4f&>(sm[5][i][0]);
    v4f* dst = out4 + (size_t)(n0 + i) * N_COMBOS + t;
#pragma unroll
    for (int k = 0; k < 4; ++k) {         // k == s0
      dst[k * 256] = (sm[0][i][k] * q) * m5;  // wave-coalesced 1 KB stores
    }
  }
}

extern "C" void kernel_launch(void* const* d_in, const int* in_sizes, int n_in,
                              void* d_out, int out_size, void* d_ws, size_t ws_size,
                              hipStream_t stream) {
  const float* m = (const float*)d_in[0];
  v4f* out = (v4f*)d_out;
  antecedents_kernel<<<N_BLOCKS, 256, 0, stream>>>(m, out);
}